// Round 3
// baseline (708.957 us; speedup 1.0000x reference)
//
#include <hip/hip_runtime.h>

#define B_TOT 262144
#define HID   256
#define NHEAD 8
#define BR    64       // rows per block
#define NTHR  256      // 4 waves

typedef __bf16 bf16_t;
typedef __attribute__((ext_vector_type(8))) __bf16 bf16x8;
typedef __attribute__((ext_vector_type(4))) __bf16 bf16x4;
typedef __attribute__((ext_vector_type(4))) float  f32x4;

// d_ws layout (bf16, fragment-ordered):
//   [0, 384K)      : QKV frags. chunk = (h*8+ks)*6 + wi*2 + half  (wi: 0=q 1=k 2=v)
//                    byte = chunk*1024 + lane*16
//                    element = W[h*32 + half*16 + (lane&15)][ks*32 + (lane>>4)*8 .. +8]
//   [384K, 512K)   : Wo frags. chunk = (wave*8+ks)*4 + jt
//                    element = Wo[wave*64 + jt*16 + (lane&15)][ks*32 + (lane>>4)*8 .. +8]
#define QKV_BYTES (384 * 1024)
#define WO_BYTES  (128 * 1024)

static __device__ __forceinline__ f32x4 mfma16(bf16x8 a, bf16x8 b, f32x4 c) {
  return __builtin_amdgcn_mfma_f32_16x16x32_bf16(a, b, c, 0, 0, 0);
}

static __device__ __forceinline__ bf16x8 cvt8(float4 a, float4 b) {
  bf16x8 r;
  r[0] = (bf16_t)a.x; r[1] = (bf16_t)a.y; r[2] = (bf16_t)a.z; r[3] = (bf16_t)a.w;
  r[4] = (bf16_t)b.x; r[5] = (bf16_t)b.y; r[6] = (bf16_t)b.z; r[7] = (bf16_t)b.w;
  return r;
}

// ---- one-shot weight pack: f32 row-major -> bf16 fragment-ordered in ws ----
__global__ __launch_bounds__(256) void pack_weights(
    const float* __restrict__ Wq, const float* __restrict__ Wk,
    const float* __restrict__ Wv, const float* __restrict__ Wo,
    bf16_t* __restrict__ ws) {
  const int t     = blockIdx.x * 256 + threadIdx.x;   // 0..32767
  const int lane  = t & 63;
  const int chunk = t >> 6;
  const int l15 = lane & 15, lg = lane >> 4;
  const float* src;
  int row, col;
  if (chunk < 384) {  // 64 (h,ks) * 6 slots
    const int slot = chunk % 6;          // wi*2 + half
    const int hk   = chunk / 6;          // h*8 + ks
    const int wi = slot >> 1, half = slot & 1;
    const int h = hk >> 3, ks = hk & 7;
    src = (wi == 0) ? Wq : (wi == 1) ? Wk : Wv;
    row = h * 32 + half * 16 + l15;
    col = ks * 32 + lg * 8;
  } else {            // Wo region: 4 waves * 8 ks * 4 jt = 128 chunks
    const int c = chunk - 384;
    const int jt = c & 3;
    const int wks = c >> 2;              // wave*8 + ks
    const int wv = wks >> 3, ks = wks & 7;
    src = Wo;
    row = wv * 64 + jt * 16 + l15;
    col = ks * 32 + lg * 8;
  }
  const float* p = src + (size_t)row * HID + col;
  const float4 a = *(const float4*)p;
  const float4 b = *(const float4*)(p + 4);
  *(bf16x8*)(ws + (size_t)t * 8) = cvt8(a, b);
}

__global__ __launch_bounds__(NTHR, 3) void fused_local_aug(
    const float* __restrict__ fine, const float* __restrict__ coarse,
    const float* __restrict__ motif, const bf16_t* __restrict__ wpk,
    const float* __restrict__ bo, float* __restrict__ out) {
  __shared__ char mlds[BR * 512];   // 64 rows x 256 bf16 (swizzled) = 32 KB

  const int tid  = threadIdx.x;
  const int lane = tid & 63;
  const int wave = tid >> 6;        // 0..3
  const int l15  = lane & 15;
  const int lg   = lane >> 4;       // 0..3
  const size_t row0 = (size_t)blockIdx.x * BR;
  const size_t mrow = row0 + wave * 16 + l15;

  // ---- preload this wave's 16 X rows into bf16 register fragments ----
  bf16x8 xm[8], xf[8], xc[8];
  {
    const float* pm = motif  + mrow * HID + lg * 8;
    const float* pf = fine   + mrow * HID + lg * 8;
    const float* pc = coarse + mrow * HID + lg * 8;
#pragma unroll
    for (int s = 0; s < 8; ++s) {
      xm[s] = cvt8(*(const float4*)(pm + s * 32), *(const float4*)(pm + s * 32 + 4));
      xf[s] = cvt8(*(const float4*)(pf + s * 32), *(const float4*)(pf + s * 32 + 4));
      xc[s] = cvt8(*(const float4*)(pc + s * 32), *(const float4*)(pc + s * 32 + 4));
    }
  }

  const char* wqkv = (const char*)wpk + (size_t)lane * 16;
  const int m_l = wave * 16 + l15;       // mid row this lane owns
  const int msw = (l15 & 7) << 4;        // swizzle (row&7 == l15&7 everywhere we use it)

#pragma unroll 1
  for (int h = 0; h < NHEAD; ++h) {
    f32x4 aQ0{}, aQ1{}, aK10{}, aK11{}, aK20{}, aK21{}, aV10{}, aV11{}, aV20{}, aV21{};
#pragma unroll
    for (int ks = 0; ks < 8; ++ks) {
      const char* p = wqkv + (size_t)((h * 8 + ks) * 6) * 1024;
      bf16x8 q0 = *(const bf16x8*)(p);
      bf16x8 q1 = *(const bf16x8*)(p + 1024);
      bf16x8 k0 = *(const bf16x8*)(p + 2048);
      bf16x8 k1 = *(const bf16x8*)(p + 3072);
      bf16x8 v0 = *(const bf16x8*)(p + 4096);
      bf16x8 v1 = *(const bf16x8*)(p + 5120);
      aQ0  = mfma16(q0, xm[ks], aQ0);   aQ1  = mfma16(q1, xm[ks], aQ1);
      aK10 = mfma16(k0, xf[ks], aK10);  aK11 = mfma16(k1, xf[ks], aK11);
      aK20 = mfma16(k0, xc[ks], aK20);  aK21 = mfma16(k1, xc[ks], aK21);
      aV10 = mfma16(v0, xf[ks], aV10);  aV11 = mfma16(v1, xf[ks], aV11);
      aV20 = mfma16(v0, xc[ks], aV20);  aV21 = mfma16(v1, xc[ks], aV21);
    }
    // scores for batch row (wave*16 + l15): reduce over reg idx + lane>>4 groups
    float s1 = 0.f, s2 = 0.f;
#pragma unroll
    for (int r = 0; r < 4; ++r) {
      s1 += aQ0[r] * aK10[r] + aQ1[r] * aK11[r];
      s2 += aQ0[r] * aK20[r] + aQ1[r] * aK21[r];
    }
    s1 += __shfl_xor(s1, 16); s1 += __shfl_xor(s1, 32);
    s2 += __shfl_xor(s2, 16); s2 += __shfl_xor(s2, 32);
    s1 *= (1.0f / 32.0f);  s2 *= (1.0f / 32.0f);   // reference divides by d_k
    const float mx = fmaxf(s1, s2);
    const float e1 = __expf(s1 - mx), e2 = __expf(s2 - mx);
    const float a1 = e1 / (e1 + e2);
    const float a2 = 1.0f - a1;
    bf16x4 o0, o1;
#pragma unroll
    for (int r = 0; r < 4; ++r) {
      o0[r] = (bf16_t)(a1 * aV10[r] + a2 * aV20[r]);
      o1[r] = (bf16_t)(a1 * aV11[r] + a2 * aV21[r]);
    }
    const int n0 = h * 32 + lg * 4;
    *(bf16x4*)(mlds + m_l * 512 + ((n0 * 2)        ^ msw)) = o0;
    *(bf16x4*)(mlds + m_l * 512 + (((n0 + 16) * 2) ^ msw)) = o1;
  }
  __syncthreads();   // mid complete

  // ---- output projection: out^T = Wo @ mid^T ; wave owns 64 output cols ----
  f32x4 acc[4][4];
#pragma unroll
  for (int jt = 0; jt < 4; ++jt)
#pragma unroll
    for (int mt = 0; mt < 4; ++mt) acc[jt][mt] = f32x4{0.f, 0.f, 0.f, 0.f};

  const char* wob = (const char*)wpk + QKV_BYTES + (size_t)lane * 16 + wave * 32768;
#pragma unroll 1
  for (int ks = 0; ks < 8; ++ks) {
    const char* p = wob + ks * 4096;
    bf16x8 wf0 = *(const bf16x8*)(p);
    bf16x8 wf1 = *(const bf16x8*)(p + 1024);
    bf16x8 wf2 = *(const bf16x8*)(p + 2048);
    bf16x8 wf3 = *(const bf16x8*)(p + 3072);
    const int kb = ks * 64 + lg * 16;
#pragma unroll
    for (int mt = 0; mt < 4; ++mt) {
      const int m = mt * 16 + l15;
      bf16x8 mf = *(const bf16x8*)(mlds + m * 512 + (kb ^ msw));
      acc[0][mt] = mfma16(wf0, mf, acc[0][mt]);
      acc[1][mt] = mfma16(wf1, mf, acc[1][mt]);
      acc[2][mt] = mfma16(wf2, mf, acc[2][mt]);
      acc[3][mt] = mfma16(wf3, mf, acc[3][mt]);
    }
  }

  // epilogue: add bias, nontemporal float4 stores
  const int j0 = wave * 64;
#pragma unroll
  for (int jt = 0; jt < 4; ++jt) {
    const int jj = j0 + jt * 16 + lg * 4;
    const float4 b4 = *(const float4*)(bo + jj);
#pragma unroll
    for (int mt = 0; mt < 4; ++mt) {
      const int m = mt * 16 + l15;
      f32x4 o;
      o[0] = acc[jt][mt][0] + b4.x;
      o[1] = acc[jt][mt][1] + b4.y;
      o[2] = acc[jt][mt][2] + b4.z;
      o[3] = acc[jt][mt][3] + b4.w;
      __builtin_nontemporal_store(o, (f32x4*)(out + (row0 + m) * HID + jj));
    }
  }
}

extern "C" void kernel_launch(void* const* d_in, const int* in_sizes, int n_in,
                              void* d_out, int out_size, void* d_ws, size_t ws_size,
                              hipStream_t stream) {
  (void)in_sizes; (void)n_in; (void)ws_size; (void)out_size;
  const float* fine   = (const float*)d_in[0];
  const float* coarse = (const float*)d_in[1];
  const float* motif  = (const float*)d_in[2];
  const float* Wq     = (const float*)d_in[3];
  const float* Wk     = (const float*)d_in[4];
  const float* Wv     = (const float*)d_in[5];
  const float* Wo     = (const float*)d_in[6];
  const float* bo     = (const float*)d_in[7];
  float* out          = (float*)d_out;
  bf16_t* wpk         = (bf16_t*)d_ws;

  pack_weights<<<128, 256, 0, stream>>>(Wq, Wk, Wv, Wo, wpk);
  fused_local_aug<<<B_TOT / BR, NTHR, 0, stream>>>(fine, coarse, motif, wpk, bo, out);
}

// Round 4
// 694.911 us; speedup vs baseline: 1.0202x; 1.0202x over previous
//
#include <hip/hip_runtime.h>

#define B_TOT 262144
#define HID   256
#define NHEAD 8
#define BR    64       // rows per block
#define NTHR  256      // 4 waves

typedef __bf16 bf16_t;
typedef __attribute__((ext_vector_type(8))) __bf16 bf16x8;
typedef __attribute__((ext_vector_type(4))) __bf16 bf16x4;
typedef __attribute__((ext_vector_type(4))) float  f32x4;

// d_ws layout (bf16, fragment-ordered; byte = chunk*1024 + lane*16):
//   QKV:  chunk = (h*8+ks)*6 + wi*2 + half   (wi: 0=q 1=k 2=v), chunk in [0,384)
//         element = W[h*32 + half*16 + (lane&15)][ks*32 + (lane>>4)*8 .. +8]
//   Wo:   chunk = 384 + ks*16 + jt, chunk in [384,512)
//         element = Wo[jt*16 + (lane&15)][ks*32 + (lane>>4)*8 .. +8]
#define QKV_BYTES (384 * 1024)

static __device__ __forceinline__ f32x4 mfma16(bf16x8 a, bf16x8 b, f32x4 c) {
  return __builtin_amdgcn_mfma_f32_16x16x32_bf16(a, b, c, 0, 0, 0);
}

static __device__ __forceinline__ bf16x8 cvt8(float4 a, float4 b) {
  bf16x8 r;
  r[0] = (bf16_t)a.x; r[1] = (bf16_t)a.y; r[2] = (bf16_t)a.z; r[3] = (bf16_t)a.w;
  r[4] = (bf16_t)b.x; r[5] = (bf16_t)b.y; r[6] = (bf16_t)b.z; r[7] = (bf16_t)b.w;
  return r;
}

// opaque register pin: forbids rematerialization of the producing loads
static __device__ __forceinline__ bf16x8 pin8(bf16x8 v) {
  f32x4 t = __builtin_bit_cast(f32x4, v);
  asm volatile("" : "+v"(t));
  return __builtin_bit_cast(bf16x8, t);
}

// ---- one-shot weight pack: f32 row-major -> bf16 fragment-ordered in ws ----
__global__ __launch_bounds__(256) void pack_weights(
    const float* __restrict__ Wq, const float* __restrict__ Wk,
    const float* __restrict__ Wv, const float* __restrict__ Wo,
    bf16_t* __restrict__ ws) {
  const int t     = blockIdx.x * 256 + threadIdx.x;   // 0..32767
  const int lane  = t & 63;
  const int chunk = t >> 6;                           // 0..511
  const int l15 = lane & 15, lg = lane >> 4;
  const float* src;
  int row, col;
  if (chunk < 384) {  // QKV: 64 (h,ks) pairs * 6 slots
    const int slot = chunk % 6;          // wi*2 + half
    const int hk   = chunk / 6;          // h*8 + ks
    const int wi = slot >> 1, half = slot & 1;
    const int h = hk >> 3, ks = hk & 7;
    src = (wi == 0) ? Wq : (wi == 1) ? Wk : Wv;
    row = h * 32 + half * 16 + l15;
    col = ks * 32 + lg * 8;
  } else {            // Wo: 8 ks * 16 jt
    const int c  = chunk - 384;
    const int ks = c >> 4, jt = c & 15;
    src = Wo;
    row = jt * 16 + l15;
    col = ks * 32 + lg * 8;
  }
  const float* p = src + (size_t)row * HID + col;
  const float4 a = *(const float4*)p;
  const float4 b = *(const float4*)(p + 4);
  *(bf16x8*)(ws + (size_t)t * 8) = cvt8(a, b);
}

__global__ __launch_bounds__(NTHR, 2) void fused_local_aug(
    const float* __restrict__ fine, const float* __restrict__ coarse,
    const float* __restrict__ motif, const bf16_t* __restrict__ wpk,
    const float* __restrict__ bo, float* __restrict__ out) {
  // wave-private mid: 4 waves x (16 rows x 256 bf16, swizzled) = 32 KB; NO barriers
  __shared__ char mlds[NTHR / 64 * 8192];

  const int tid  = threadIdx.x;
  const int lane = tid & 63;
  const int wave = tid >> 6;        // 0..3
  const int l15  = lane & 15;
  const int lg   = lane >> 4;       // 0..3
  const size_t row0 = (size_t)blockIdx.x * BR;
  const size_t mrow = row0 + wave * 16 + l15;   // this lane's batch row (= its mid row)

  char* mwave = mlds + wave * 8192;         // this wave's mid region
  const int msw = (l15 & 7) << 4;           // row swizzle (row == l15)

  // ---- preload this wave's 16 X rows into PINNED bf16 register fragments ----
  bf16x8 xm[8], xf[8], xc[8];
  {
    const float* pm = motif  + mrow * HID + lg * 8;
    const float* pf = fine   + mrow * HID + lg * 8;
    const float* pc = coarse + mrow * HID + lg * 8;
#pragma unroll
    for (int s = 0; s < 8; ++s) {
      xm[s] = pin8(cvt8(*(const float4*)(pm + s * 32), *(const float4*)(pm + s * 32 + 4)));
      xf[s] = pin8(cvt8(*(const float4*)(pf + s * 32), *(const float4*)(pf + s * 32 + 4)));
      xc[s] = pin8(cvt8(*(const float4*)(pc + s * 32), *(const float4*)(pc + s * 32 + 4)));
    }
  }

  const char* wqkv = (const char*)wpk + (size_t)lane * 16;

#pragma unroll 1
  for (int h = 0; h < NHEAD; ++h) {
    f32x4 aQ0{}, aQ1{}, aK10{}, aK11{}, aK20{}, aK21{}, aV10{}, aV11{}, aV20{}, aV21{};
    const char* ph = wqkv + (size_t)h * 49152;
#pragma unroll
    for (int ks = 0; ks < 8; ++ks) {
      const char* p = ph + ks * 6144;
      bf16x8 q0 = *(const bf16x8*)(p);
      bf16x8 q1 = *(const bf16x8*)(p + 1024);
      bf16x8 k0 = *(const bf16x8*)(p + 2048);
      bf16x8 k1 = *(const bf16x8*)(p + 3072);
      bf16x8 v0 = *(const bf16x8*)(p + 4096);
      bf16x8 v1 = *(const bf16x8*)(p + 5120);
      aQ0  = mfma16(q0, xm[ks], aQ0);   aQ1  = mfma16(q1, xm[ks], aQ1);
      aK10 = mfma16(k0, xf[ks], aK10);  aK11 = mfma16(k1, xf[ks], aK11);
      aK20 = mfma16(k0, xc[ks], aK20);  aK21 = mfma16(k1, xc[ks], aK21);
      aV10 = mfma16(v0, xf[ks], aV10);  aV11 = mfma16(v1, xf[ks], aV11);
      aV20 = mfma16(v0, xc[ks], aV20);  aV21 = mfma16(v1, xc[ks], aV21);
    }
    // scores for this lane's batch row: reduce over reg idx + lane>>4 groups
    float s1 = 0.f, s2 = 0.f;
#pragma unroll
    for (int r = 0; r < 4; ++r) {
      s1 += aQ0[r] * aK10[r] + aQ1[r] * aK11[r];
      s2 += aQ0[r] * aK20[r] + aQ1[r] * aK21[r];
    }
    s1 += __shfl_xor(s1, 16); s1 += __shfl_xor(s1, 32);
    s2 += __shfl_xor(s2, 16); s2 += __shfl_xor(s2, 32);
    s1 *= (1.0f / 32.0f);  s2 *= (1.0f / 32.0f);   // reference divides by d_k
    const float mx = fmaxf(s1, s2);
    const float e1 = __expf(s1 - mx), e2 = __expf(s2 - mx);
    const float a1 = e1 / (e1 + e2);
    const float a2 = 1.0f - a1;
    bf16x4 o0, o1;
#pragma unroll
    for (int r = 0; r < 4; ++r) {
      o0[r] = (bf16_t)(a1 * aV10[r] + a2 * aV20[r]);
      o1[r] = (bf16_t)(a1 * aV11[r] + a2 * aV21[r]);
    }
    const int n0 = h * 32 + lg * 4;
    *(bf16x4*)(mwave + l15 * 512 + ((n0 * 2)        ^ msw)) = o0;
    *(bf16x4*)(mwave + l15 * 512 + (((n0 + 16) * 2) ^ msw)) = o1;
  }
  // no barrier: each lane reads back only its own mid row (wave-local LDS)

  // ---- output projection: wave computes ALL 256 out cols of its 16 rows ----
  f32x4 acc[16];
#pragma unroll
  for (int jt = 0; jt < 16; ++jt) acc[jt] = f32x4{0.f, 0.f, 0.f, 0.f};

  const char* wob = (const char*)wpk + QKV_BYTES + (size_t)lane * 16;
#pragma unroll
  for (int ks = 0; ks < 8; ++ks) {
    const int kb = ks * 64 + lg * 16;
    bf16x8 mf = *(const bf16x8*)(mwave + l15 * 512 + (kb ^ msw));
    const char* p = wob + ks * 16384;
#pragma unroll
    for (int jt = 0; jt < 16; ++jt) {
      bf16x8 wf = *(const bf16x8*)(p + jt * 1024);
      acc[jt] = mfma16(wf, mf, acc[jt]);
    }
  }

  // epilogue: add bias, nontemporal float4 stores (C: col=l15 -> m, row=lg*4+r -> j)
#pragma unroll
  for (int jt = 0; jt < 16; ++jt) {
    const int jj = jt * 16 + lg * 4;
    const float4 b4 = *(const float4*)(bo + jj);
    f32x4 o;
    o[0] = acc[jt][0] + b4.x;
    o[1] = acc[jt][1] + b4.y;
    o[2] = acc[jt][2] + b4.z;
    o[3] = acc[jt][3] + b4.w;
    __builtin_nontemporal_store(o, (f32x4*)(out + mrow * HID + jj));
  }
}

extern "C" void kernel_launch(void* const* d_in, const int* in_sizes, int n_in,
                              void* d_out, int out_size, void* d_ws, size_t ws_size,
                              hipStream_t stream) {
  (void)in_sizes; (void)n_in; (void)ws_size; (void)out_size;
  const float* fine   = (const float*)d_in[0];
  const float* coarse = (const float*)d_in[1];
  const float* motif  = (const float*)d_in[2];
  const float* Wq     = (const float*)d_in[3];
  const float* Wk     = (const float*)d_in[4];
  const float* Wv     = (const float*)d_in[5];
  const float* Wo     = (const float*)d_in[6];
  const float* bo     = (const float*)d_in[7];
  float* out          = (float*)d_out;
  bf16_t* wpk         = (bf16_t*)d_ws;

  pack_weights<<<128, 256, 0, stream>>>(Wq, Wk, Wv, Wo, wpk);
  fused_local_aug<<<B_TOT / BR, NTHR, 0, stream>>>(fine, coarse, motif, wpk, bo, out);
}